// Round 7
// baseline (4696.250 us; speedup 1.0000x reference)
//
#include <hip/hip_runtime.h>

// LSTM B=64 T=512 IN=512 H=1024 OUT=512, all fp32 in/out.
// Persistent-RNN. R6: FLAGLESS exchange — h values carry their own timestep.
//   enc = h*0.4 + (t&3)  stored as f32 (sc0 sc1, LLC write-through).
//   Consumers poll-load the data itself; per-producer-fragment freshness check
//   (fresh: |enc-k|<0.5). No flags, no store-ack, no publish: 1 LLC RT exchange.
//   Mod-4 buckets disambiguate same-buffer overwrites (lag<=1 proof in R6 notes).
//   red[] double-buffered -> ONE __syncthreads per step.
//   x(t+1) loads overlap MFMA/epilogue; consumed via vmcnt(1) (h-store excluded).

#define B_   64
#define T_   512
#define IN_  512
#define H_   1024
#define G4_  4096   // 4*H
#define OUT_ 512

typedef _Float16 f16;
typedef _Float16 f16x8 __attribute__((ext_vector_type(8)));
typedef _Float16 f16x4 __attribute__((ext_vector_type(4)));
typedef float f32x4  __attribute__((ext_vector_type(4)));
typedef float f32x16 __attribute__((ext_vector_type(16)));

// workspace layout (bytes)
#define X16_OFF   0UL                         // [64][512][512] f16 = 33554432
#define WOT_OFF   33554432UL                  // W_out^T [512][1024] f16 = 1048576
#define H_OFF     (WOT_OFF + 1048576UL)       // h: [2 grp][2 buf][32][1024] f32 = 524288
#define WS_NEED   (H_OFF + 524288UL)
#define ZERO_BYTES 524288UL                   // h only (0.0 = enc(h=0, bucket 0))

#define ENCK 0.4f
#define DECK 2.5f

__device__ __forceinline__ float sigmoidf_(float v) { return 1.f / (1.f + __expf(-v)); }
__device__ __forceinline__ float tanhf_(float v) { return 1.f - 2.f / (__expf(2.f * v) + 1.f); }

// Agent-coherent loads/stores: bypass L1 (sc0) and non-coherent per-XCD L2 (sc1).
__device__ __forceinline__ f32x4 ld_agent_f32x4(const float* p) {
  f32x4 r;
  asm volatile("global_load_dwordx4 %0, %1, off sc0 sc1" : "=v"(r) : "v"(p));
  return r;
}
__device__ __forceinline__ void st_agent_f32(float* p, float v) {
  asm volatile("global_store_dword %0, %1, off sc0 sc1" :: "v"(p), "v"(v) : "memory");
}

// s_waitcnt + scheduler fence (rule #18: keep dependent ALU below the wait).
__device__ __forceinline__ void wait_vm0() {
  asm volatile("s_waitcnt vmcnt(0)" ::: "memory");
  __builtin_amdgcn_sched_barrier(0);
}
__device__ __forceinline__ void wait_vm1() {
  asm volatile("s_waitcnt vmcnt(1)" ::: "memory");
  __builtin_amdgcn_sched_barrier(0);
}

__global__ __launch_bounds__(256) void lstm_prepass(
    const float* __restrict__ x, const float* __restrict__ Wout,
    f16* __restrict__ x16, f16* __restrict__ WoT) {
  long i = (long)blockIdx.x * blockDim.x + threadIdx.x;
  long stride = (long)gridDim.x * blockDim.x;
  const long n4 = (long)B_ * T_ * IN_ / 4;
  const float4* x4 = (const float4*)x;
  f16x4* o4 = (f16x4*)x16;
  for (long p = i; p < n4; p += stride) {
    float4 v = x4[p];
    f16x4 o = { (f16)v.x, (f16)v.y, (f16)v.z, (f16)v.w };
    o4[p] = o;
  }
  const long nw = (long)H_ * OUT_;
  for (long p = i; p < nw; p += stride) {
    long k = p / OUT_, c = p % OUT_;
    WoT[c * (long)H_ + k] = (f16)Wout[p];
  }
}

// 128 WGs x 512 threads (8 waves). WG wg: group g = wg>>6 (rows g*32..g*32+31),
// wgi = wg&63 owns h-cols [wgi*16, wgi*16+16). 8 waves K-split over K=1536.
// Wave w's h K-range [128w,128w+128); its frag kf maps 1:1 to producer WG 8w+kf.
__global__ __launch_bounds__(512, 2) void lstm_main(
    const float* __restrict__ W, const float* __restrict__ b,
    const f16* __restrict__ x16, float* hbuf) {

  const int wg   = blockIdx.x;
  const int g    = wg >> 6;
  const int wgi  = wg & 63;
  const int tid  = threadIdx.x;
  const int wave = tid >> 6;    // 0..7
  const int lane = tid & 63;

  const int hbase   = wgi * 16;
  const int colLane = lane & 31;        // MFMA N index within tile
  const int khalf   = (lane >> 5) * 8;  // MFMA K sub-index
  const int arow    = lane & 31;        // MFMA M index (batch row in group)

  // ---- persistent W fragments (fp32 -> fp16, MFMA B layout), as R5 ----
  f16x8 wf[24];
  #pragma unroll
  for (int n = 0; n < 2; ++n) {
    const int gate = n * 2 + (colLane >> 4);
    const int gcol = gate * H_ + hbase + (colLane & 15);
    #pragma unroll
    for (int kf = 0; kf < 12; ++kf) {
      const int k0 = (kf < 4) ? (64 * wave + 16 * kf)
                              : (512 + 128 * wave + 16 * (kf - 4));
      f16x8 v;
      #pragma unroll
      for (int j = 0; j < 8; ++j)
        v[j] = (f16)W[(long)(k0 + khalf + j) * G4_ + gcol];
      wf[n * 12 + kf] = v;
    }
  }

  // epilogue ownership: thread -> (row erow 0..31, col offset ej 0..15)
  const int erow = tid >> 4;
  const int ej   = tid & 15;
  float bias[4];
  #pragma unroll
  for (int gt = 0; gt < 4; ++gt) bias[gt] = b[gt * H_ + hbase + ej];

  float c_state = 0.f;

  __shared__ float red[2][8][32][68];  // double-buffered -> 1 barrier/step

  const f16* xg = x16 + (long)(g * 32) * T_ * IN_;
  float* hb     = hbuf + (long)g * 2 * 32 * H_;   // [2][32][1024] f32 (encoded)

  // ---- x-part of t=0 ----
  f32x16 acc0 = {}, acc1 = {};
  {
    const f16* xrow = xg + (long)arow * (T_ * IN_) + 64 * wave + khalf;
    f16x8 xa[4];
    #pragma unroll
    for (int f = 0; f < 4; ++f) xa[f] = *(const f16x8*)(xrow + 16 * f);
    #pragma unroll
    for (int kf = 0; kf < 4; ++kf) {
      acc0 = __builtin_amdgcn_mfma_f32_32x32x16_f16(xa[kf], wf[kf],      acc0, 0, 0, 0);
      acc1 = __builtin_amdgcn_mfma_f32_32x32x16_f16(xa[kf], wf[12 + kf], acc1, 0, 0, 0);
    }
  }

  for (int t = 0; t < T_; ++t) {
    // ---- flagless h_t acquire: poll-load + per-frag bucket check ----
    f16x8 ha[8];
    {
      const float kf32 = (float)(t & 3);
      const float* hp = hb + (long)(t & 1) * (32 * H_) + (long)arow * H_
                           + 128 * wave + khalf;
      f32x4 hs0[8], hs1[8];
      unsigned pend = 0xFFu;
      int guard = 0;
      while (pend && ++guard < (1 << 22)) {
        #pragma unroll
        for (int kf = 0; kf < 8; ++kf)
          if (pend & (1u << kf)) {
            hs0[kf] = ld_agent_f32x4(hp + 16 * kf);
            hs1[kf] = ld_agent_f32x4(hp + 16 * kf + 4);
          }
        wait_vm0();   // also drains my step t-1 h-stores (same-addr WAW order)
        #pragma unroll
        for (int kf = 0; kf < 8; ++kf)
          if (pend & (1u << kf)) {
            float d0 = hs0[kf][0] - kf32, d1 = hs0[kf][1] - kf32;
            float d2 = hs0[kf][2] - kf32, d3 = hs0[kf][3] - kf32;
            float d4 = hs1[kf][0] - kf32, d5 = hs1[kf][1] - kf32;
            float d6 = hs1[kf][2] - kf32, d7 = hs1[kf][3] - kf32;
            float m = fmaxf(fmaxf(fmaxf(fabsf(d0), fabsf(d1)),
                                  fmaxf(fabsf(d2), fabsf(d3))),
                            fmaxf(fmaxf(fabsf(d4), fabsf(d5)),
                                  fmaxf(fabsf(d6), fabsf(d7))));
            if (!__any(m > 0.5f)) {   // all 64 lanes fresh for this producer
              f16x8 v;
              v[0] = (f16)(d0 * DECK); v[1] = (f16)(d1 * DECK);
              v[2] = (f16)(d2 * DECK); v[3] = (f16)(d3 * DECK);
              v[4] = (f16)(d4 * DECK); v[5] = (f16)(d5 * DECK);
              v[6] = (f16)(d6 * DECK); v[7] = (f16)(d7 * DECK);
              ha[kf] = v;
              pend &= ~(1u << kf);
            }
          }
      }
    }

    // ---- issue x(t+1) loads now; consumed after epilogue via vmcnt(1) ----
    f16x8 xa[4];
    if (t + 1 < T_) {
      const f16* xrow = xg + (long)arow * (T_ * IN_) + (long)(t + 1) * IN_
                           + 64 * wave + khalf;
      #pragma unroll
      for (int f = 0; f < 4; ++f) xa[f] = *(const f16x8*)(xrow + 16 * f);
    }

    // ---- h-part MFMAs ----
    #pragma unroll
    for (int kf = 0; kf < 8; ++kf) {
      acc0 = __builtin_amdgcn_mfma_f32_32x32x16_f16(ha[kf], wf[4 + kf],  acc0, 0, 0, 0);
      acc1 = __builtin_amdgcn_mfma_f32_32x32x16_f16(ha[kf], wf[16 + kf], acc1, 0, 0, 0);
    }

    // ---- cross-wave K-reduction via LDS (double-buffered, 1 barrier) ----
    // C layout (32x32): col = lane&31, row = (r&3) + 8*(r>>2) + 4*(lane>>5)
    {
      float (*rb)[32][68] = red[t & 1];
      #pragma unroll
      for (int r = 0; r < 16; ++r) {
        const int row = (r & 3) + 8 * (r >> 2) + 4 * (lane >> 5);
        rb[wave][row][colLane]      = acc0[r];
        rb[wave][row][32 + colLane] = acc1[r];
      }
    }
    __syncthreads();

    // ---- epilogue: gates, c/h update, encoded f32 store ----
    {
      const float (*rb)[32][68] = red[t & 1];
      float f4[4];
      #pragma unroll
      for (int gt = 0; gt < 4; ++gt) {
        float s = bias[gt];
        #pragma unroll
        for (int w = 0; w < 8; ++w) s += rb[w][erow][gt * 16 + ej];
        f4[gt] = s;
      }
      const float fg = sigmoidf_(f4[0]);
      const float ig = sigmoidf_(f4[1]);
      const float gg = tanhf_(f4[2]);
      const float og = sigmoidf_(f4[3]);
      c_state = c_state * fg + ig * gg;
      const float hv  = og * tanhf_(c_state);
      const float enc = fmaf(hv, ENCK, (float)((t + 1) & 3));
      st_agent_f32(&hb[(long)((t + 1) & 1) * (32 * H_) + (long)erow * H_ + hbase + ej],
                   enc);
    }

    // ---- x-part of t+1 (waits x loads only; h-store ack NOT on path) ----
    acc0 = f32x16{}; acc1 = f32x16{};
    if (t + 1 < T_) {
      wait_vm1();   // 4 x-loads older than the 1 store -> x complete
      #pragma unroll
      for (int kf = 0; kf < 4; ++kf) {
        acc0 = __builtin_amdgcn_mfma_f32_32x32x16_f16(xa[kf], wf[kf],      acc0, 0, 0, 0);
        acc1 = __builtin_amdgcn_mfma_f32_32x32x16_f16(xa[kf], wf[12 + kf], acc1, 0, 0, 0);
      }
    }
  }
}

// out = h_T @ W_out + b_out : [64,1024]@[1024,512]. h_T encoded (bucket 0) in
// buf 0. 128 WGs: 4 row-tiles x 32 col-tiles of 16x16; 4 waves K-split 256.
__global__ __launch_bounds__(256) void lstm_out(
    const float* __restrict__ hbuf, const f16* __restrict__ WoT,
    const float* __restrict__ bout, float* __restrict__ out) {
  const int wgid = blockIdx.x;
  const int rowT = wgid >> 5;   // 0..3
  const int colT = wgid & 31;   // 0..31
  const int tid  = threadIdx.x;
  const int wave = tid >> 6;
  const int lane = tid & 63;
  const int r16  = lane & 15;
  const int ksel = (lane >> 4) * 8;

  const int g = rowT >> 1;
  const float* hrow = hbuf + (long)g * 2 * 32 * H_            // group base, buf 0
                    + (long)((rowT & 1) * 16 + r16) * H_;
  const f16* wrow = WoT + (long)(colT * 16 + r16) * H_;

  f32x4 acc = {};
  #pragma unroll
  for (int f = 0; f < 8; ++f) {
    const float* p = hrow + 256 * wave + 32 * f + ksel;
    f16x8 a;
    #pragma unroll
    for (int j = 0; j < 8; ++j) a[j] = (f16)(p[j] * DECK);   // decode bucket 0
    f16x8 bf = *(const f16x8*)(wrow + 256 * wave + 32 * f + ksel);
    acc = __builtin_amdgcn_mfma_f32_16x16x32_f16(a, bf, acc, 0, 0, 0);
  }

  __shared__ float red[4][16][20];
  #pragma unroll
  for (int r = 0; r < 4; ++r)
    red[wave][(lane >> 4) * 4 + r][lane & 15] = acc[r];
  __syncthreads();

  const int row = tid >> 4;   // 0..15
  const int col = tid & 15;
  float s = bout[colT * 16 + col];
  #pragma unroll
  for (int w = 0; w < 4; ++w) s += red[w][row][col];
  out[(long)(rowT * 16 + row) * OUT_ + colT * 16 + col] = s;
}

extern "C" void kernel_launch(void* const* d_in, const int* in_sizes, int n_in,
                              void* d_out, int out_size, void* d_ws, size_t ws_size,
                              hipStream_t stream) {
  const float* x    = (const float*)d_in[0];
  const float* W    = (const float*)d_in[1];
  const float* b    = (const float*)d_in[2];
  const float* Wout = (const float*)d_in[3];
  const float* bout = (const float*)d_in[4];
  float* out = (float*)d_out;

  if (ws_size < WS_NEED) return;  // avoid corrupting memory if ws too small

  char* wsb = (char*)d_ws;
  f16* x16    = (f16*)(wsb + X16_OFF);
  f16* WoT    = (f16*)(wsb + WOT_OFF);
  float* hbuf = (float*)(wsb + H_OFF);

  // h buffers to 0.0 == enc(h=0, bucket 0): valid h_0 in buf0, stale in buf1.
  hipMemsetAsync(wsb + H_OFF, 0, ZERO_BYTES, stream);

  lstm_prepass<<<1024, 256, 0, stream>>>(x, Wout, x16, WoT);

  // 128 WGs x 512 threads, 1 per CU.
  lstm_main<<<128, 512, 0, stream>>>(W, b, x16, hbuf);

  lstm_out<<<128, 256, 0, stream>>>(hbuf, WoT, bout, out);
}

// Round 9
// 2441.829 us; speedup vs baseline: 1.9233x; 1.9233x over previous
//
#include <hip/hip_runtime.h>

// LSTM B=64 T=512 IN=512 H=1024 OUT=512, all fp32 in/out.
// Persistent-RNN. R8 = R5 skeleton (best: 2450us) + serial-chain cuts:
//  - per-(WG,wave) flags: each wave scatter-stores its own h rows, acks its
//    own stores, publishes its own flag -> NO barrier in the publish tail
//  - consumer waves poll their 64 producer-wave words (1 load/lane) with a
//    dual-outstanding rolling poll (vmcnt(1)) -> detect granularity ~RT/2
//  - red[] double-buffered -> ONE __syncthreads per step
// Grid 128 WGs, 139KB LDS -> 1 WG/CU, 2x co-residency headroom (R7 lesson:
// never launch a persistent grid at exactly resident capacity).

#define B_   64
#define T_   512
#define IN_  512
#define H_   1024
#define G4_  4096   // 4*H
#define OUT_ 512

typedef _Float16 f16;
typedef _Float16 f16x8 __attribute__((ext_vector_type(8)));
typedef _Float16 f16x4 __attribute__((ext_vector_type(4)));
typedef float f32x4  __attribute__((ext_vector_type(4)));
typedef float f32x16 __attribute__((ext_vector_type(16)));

// workspace layout (bytes)
#define X16_OFF   0UL                         // [64][512][512] f16 = 33554432
#define WOT_OFF   33554432UL                  // W_out^T [512][1024] f16 = 1048576
#define H_OFF     (WOT_OFF + 1048576UL)       // h: [2 grp][2 buf][32][1024] f16 = 262144
#define FLG_OFF   (H_OFF + 262144UL)          // flags: [2 grp][64 slot][8 wave] u32 = 4096
#define WS_NEED   (FLG_OFF + 4096UL)
#define ZERO_BYTES (262144UL + 4096UL)        // h + flags zeroed together

__device__ __forceinline__ float sigmoidf_(float v) { return 1.f / (1.f + __expf(-v)); }
__device__ __forceinline__ float tanhf_(float v) { return 1.f - 2.f / (__expf(2.f * v) + 1.f); }

// Agent-coherent ops: bypass L1 (sc0) and non-coherent per-XCD L2 (sc1).
__device__ __forceinline__ f16x8 ld_agent_b128(const f16* p) {
  f16x8 r;
  asm volatile("global_load_dwordx4 %0, %1, off sc0 sc1" : "=v"(r) : "v"(p));
  return r;
}
__device__ __forceinline__ void st_agent_b16(f16* p, f16 v) {
  unsigned int u = (unsigned int)__builtin_bit_cast(unsigned short, v);
  asm volatile("global_store_short %0, %1, off sc0 sc1" :: "v"(p), "v"(u) : "memory");
}
__device__ __forceinline__ void st_agent_b32(unsigned* p, unsigned v) {
  asm volatile("global_store_dword %0, %1, off sc0 sc1" :: "v"(p), "v"(v) : "memory");
}
// Flag load: issued async; NOT ready until an explicit s_waitcnt.
__device__ __forceinline__ unsigned ld_flag(const unsigned* p) {
  unsigned r;
  asm volatile("global_load_dword %0, %1, off sc0 sc1" : "=v"(r) : "v"(p));
  return r;
}
__device__ __forceinline__ void wait_vm0() {
  asm volatile("s_waitcnt vmcnt(0)" ::: "memory");
  __builtin_amdgcn_sched_barrier(0);
}
__device__ __forceinline__ void wait_vm1() {
  asm volatile("s_waitcnt vmcnt(1)" ::: "memory");
  __builtin_amdgcn_sched_barrier(0);
}

__global__ __launch_bounds__(256) void lstm_prepass(
    const float* __restrict__ x, const float* __restrict__ Wout,
    f16* __restrict__ x16, f16* __restrict__ WoT) {
  long i = (long)blockIdx.x * blockDim.x + threadIdx.x;
  long stride = (long)gridDim.x * blockDim.x;
  const long n4 = (long)B_ * T_ * IN_ / 4;
  const float4* x4 = (const float4*)x;
  f16x4* o4 = (f16x4*)x16;
  for (long p = i; p < n4; p += stride) {
    float4 v = x4[p];
    f16x4 o = { (f16)v.x, (f16)v.y, (f16)v.z, (f16)v.w };
    o4[p] = o;
  }
  const long nw = (long)H_ * OUT_;
  for (long p = i; p < nw; p += stride) {
    long k = p / OUT_, c = p % OUT_;
    WoT[c * (long)H_ + k] = (f16)Wout[p];
  }
}

// 128 WGs x 512 threads (8 waves). WG wg: group g = wg>>6 (rows g*32..g*32+31),
// wgi = wg&63 owns h-cols [wgi*16, wgi*16+16). 8 waves K-split over K=1536
// (x 64/wave, h 128/wave). Wave w's h K-range [128w,128w+128) is produced by
// slots 8w..8w+7; per-(slot,wave) flags -> consumer window = 64 contiguous u32.
__global__ __launch_bounds__(512, 2) void lstm_main(
    const float* __restrict__ W, const float* __restrict__ b,
    const f16* __restrict__ x16, f16* hbuf, unsigned* flags) {

  const int wg   = blockIdx.x;
  const int g    = wg >> 6;
  const int wgi  = wg & 63;
  const int tid  = threadIdx.x;
  const int wave = tid >> 6;    // 0..7
  const int lane = tid & 63;

  const int hbase   = wgi * 16;
  const int colLane = lane & 31;        // MFMA N index within tile
  const int khalf   = (lane >> 5) * 8;  // MFMA K sub-index
  const int arow    = lane & 31;        // MFMA M index (batch row in group)

  // ---- persistent W fragments (fp32 -> fp16, MFMA B layout), as R5 ----
  // frag f = n*12 + kf: N-tile n in {0,1}; kf<4 = x (k0=64w+16kf),
  // kf in [4,12) = h (k0=512+128w+16(kf-4)). Local col c = n*32+colLane:
  // gate = c>>4, hcol = hbase + (c&15).
  f16x8 wf[24];
  #pragma unroll
  for (int n = 0; n < 2; ++n) {
    const int gate = n * 2 + (colLane >> 4);
    const int gcol = gate * H_ + hbase + (colLane & 15);
    #pragma unroll
    for (int kf = 0; kf < 12; ++kf) {
      const int k0 = (kf < 4) ? (64 * wave + 16 * kf)
                              : (512 + 128 * wave + 16 * (kf - 4));
      f16x8 v;
      #pragma unroll
      for (int j = 0; j < 8; ++j)
        v[j] = (f16)W[(long)(k0 + khalf + j) * G4_ + gcol];
      wf[n * 12 + kf] = v;
    }
  }

  // epilogue ownership: thread -> (row erow 0..31, col offset ej 0..15).
  // wave v's epilogue threads cover rows 4v..4v+3 (tid>>4 >> 2 == wave).
  const int erow = tid >> 4;
  const int ej   = tid & 15;
  float bias[4];
  #pragma unroll
  for (int gt = 0; gt < 4; ++gt) bias[gt] = b[gt * H_ + hbase + ej];

  float c_state = 0.f;

  __shared__ float red[2][8][32][68];   // double-buffered -> 1 barrier/step

  const f16* xg = x16 + (long)(g * 32) * T_ * IN_;
  f16* hb       = hbuf + (long)g * 2 * 32 * H_;   // [2][32][1024]
  unsigned* flg = flags + g * 64 * 8;             // [slot][wave]

  // my poll word: (slot 8w + (lane>>3), wave lane&7) = flg[64*wave + lane]
  const unsigned* fp = flg + 64 * wave + lane;
  // my flag word (published by lane 0)
  unsigned* myflag = flg + wgi * 8 + wave;

  // ---- x-part of t=0 (h0 = 0 pre-zeroed in ws) ----
  f32x16 acc0 = {}, acc1 = {};
  {
    const f16* xrow = xg + (long)arow * (T_ * IN_) + 64 * wave + khalf;
    f16x8 xa[4];
    #pragma unroll
    for (int f = 0; f < 4; ++f) xa[f] = *(const f16x8*)(xrow + 16 * f);
    #pragma unroll
    for (int kf = 0; kf < 4; ++kf) {
      acc0 = __builtin_amdgcn_mfma_f32_32x32x16_f16(xa[kf], wf[kf],      acc0, 0, 0, 0);
      acc1 = __builtin_amdgcn_mfma_f32_32x32x16_f16(xa[kf], wf[12 + kf], acc1, 0, 0, 0);
    }
  }

  for (int t = 0; t < T_; ++t) {
    const int buf = t & 1;

    // ---- dual-outstanding rolling poll: my 64 producer-wave flags >= t ----
    if (t > 0) {
      const unsigned tgt = (unsigned)t;
      int guard = 0;
      unsigned v0 = ld_flag(fp);
      unsigned v1 = 0;
      for (;;) {
        v1 = ld_flag(fp);
        wait_vm1();                       // oldest (v0) retired
        if (__all(v0 >= tgt) || ++guard > (1 << 22)) break;
        v0 = ld_flag(fp);
        wait_vm1();                       // oldest (v1) retired
        if (__all(v1 >= tgt) || ++guard > (1 << 22)) break;
      }
      // retire the leftover in-flight poll load before its reg can be reused
      asm volatile("s_waitcnt vmcnt(0)" ::: "memory");
      asm volatile("" :: "v"(v0), "v"(v1));   // keep regs alive past drain
      __builtin_amdgcn_sched_barrier(0);
    }

    // ---- h-part: agent-coherent loads of my K-range of h_t ----
    {
      const f16* hrow = hb + (long)buf * (32 * H_) + (long)arow * H_
                           + 128 * wave + khalf;
      f16x8 ha[8];
      #pragma unroll
      for (int f = 0; f < 8; ++f)
        ha[f] = ld_agent_b128(hrow + 16 * f);
      wait_vm0();
      #pragma unroll
      for (int kf = 0; kf < 8; ++kf) {
        acc0 = __builtin_amdgcn_mfma_f32_32x32x16_f16(ha[kf], wf[4 + kf],  acc0, 0, 0, 0);
        acc1 = __builtin_amdgcn_mfma_f32_32x32x16_f16(ha[kf], wf[16 + kf], acc1, 0, 0, 0);
      }
    }

    // ---- cross-wave K-reduction via LDS (double-buffered) ----
    // C layout (32x32): col = lane&31, row = (r&3) + 8*(r>>2) + 4*(lane>>5)
    {
      float (*rb)[32][68] = red[buf];
      #pragma unroll
      for (int r = 0; r < 16; ++r) {
        const int row = (r & 3) + 8 * (r >> 2) + 4 * (lane >> 5);
        rb[wave][row][colLane]      = acc0[r];
        rb[wave][row][32 + colLane] = acc1[r];
      }
    }
    __syncthreads();   // the ONLY barrier per step

    // ---- epilogue: gates, c/h update, direct scatter store, per-wave flag --
    {
      const float (*rb)[32][68] = red[buf];
      float f4[4];
      #pragma unroll
      for (int gt = 0; gt < 4; ++gt) {
        float s = bias[gt];
        #pragma unroll
        for (int w = 0; w < 8; ++w) s += rb[w][erow][gt * 16 + ej];
        f4[gt] = s;
      }
      const float fg = sigmoidf_(f4[0]);
      const float ig = sigmoidf_(f4[1]);
      const float gg = tanhf_(f4[2]);
      const float og = sigmoidf_(f4[3]);
      c_state = c_state * fg + ig * gg;
      const float hv = og * tanhf_(c_state);
      st_agent_b16(&hb[(long)(buf ^ 1) * (32 * H_) + (long)erow * H_ + hbase + ej],
                   (f16)hv);
      wait_vm0();                         // ack THIS wave's 64 stores only
      if (lane == 0)
        st_agent_b32(myflag, (unsigned)(t + 1));
    }

    // ---- x-part of t+1 (after publish; never delays it) ----
    acc0 = f32x16{}; acc1 = f32x16{};
    if (t + 1 < T_) {
      const f16* xrow = xg + (long)arow * (T_ * IN_) + (long)(t + 1) * IN_
                           + 64 * wave + khalf;
      f16x8 xa[4];
      #pragma unroll
      for (int f = 0; f < 4; ++f) xa[f] = *(const f16x8*)(xrow + 16 * f);
      #pragma unroll
      for (int kf = 0; kf < 4; ++kf) {
        acc0 = __builtin_amdgcn_mfma_f32_32x32x16_f16(xa[kf], wf[kf],      acc0, 0, 0, 0);
        acc1 = __builtin_amdgcn_mfma_f32_32x32x16_f16(xa[kf], wf[12 + kf], acc1, 0, 0, 0);
      }
    }
  }
}

// out = h_T @ W_out + b_out : [64,1024]@[1024,512]. h_T is in h buf 0 (T even).
// 128 WGs: 4 row-tiles x 32 col-tiles of 16x16; 4 waves K-split 256 each.
__global__ __launch_bounds__(256) void lstm_out(
    const f16* __restrict__ hbuf, const f16* __restrict__ WoT,
    const float* __restrict__ bout, float* __restrict__ out) {
  const int wgid = blockIdx.x;
  const int rowT = wgid >> 5;   // 0..3
  const int colT = wgid & 31;   // 0..31
  const int tid  = threadIdx.x;
  const int wave = tid >> 6;
  const int lane = tid & 63;
  const int r16  = lane & 15;
  const int ksel = (lane >> 4) * 8;

  const int g = rowT >> 1;
  const f16* hrow = hbuf + (long)g * 2 * 32 * H_            // group base (buf 0)
                  + (long)((rowT & 1) * 16 + r16) * H_;
  const f16* wrow = WoT + (long)(colT * 16 + r16) * H_;

  f32x4 acc = {};
  #pragma unroll
  for (int f = 0; f < 8; ++f) {
    f16x8 a  = *(const f16x8*)(hrow + 256 * wave + 32 * f + ksel);
    f16x8 bf = *(const f16x8*)(wrow + 256 * wave + 32 * f + ksel);
    acc = __builtin_amdgcn_mfma_f32_16x16x32_f16(a, bf, acc, 0, 0, 0);
  }

  __shared__ float red[4][16][20];
  #pragma unroll
  for (int r = 0; r < 4; ++r)
    red[wave][(lane >> 4) * 4 + r][lane & 15] = acc[r];
  __syncthreads();

  const int row = tid >> 4;   // 0..15
  const int col = tid & 15;
  float s = bout[colT * 16 + col];
  #pragma unroll
  for (int w = 0; w < 4; ++w) s += red[w][row][col];
  out[(long)(rowT * 16 + row) * OUT_ + colT * 16 + col] = s;
}

extern "C" void kernel_launch(void* const* d_in, const int* in_sizes, int n_in,
                              void* d_out, int out_size, void* d_ws, size_t ws_size,
                              hipStream_t stream) {
  const float* x    = (const float*)d_in[0];
  const float* W    = (const float*)d_in[1];
  const float* b    = (const float*)d_in[2];
  const float* Wout = (const float*)d_in[3];
  const float* bout = (const float*)d_in[4];
  float* out = (float*)d_out;

  if (ws_size < WS_NEED) return;  // avoid corrupting memory if ws too small

  char* wsb = (char*)d_ws;
  f16* x16  = (f16*)(wsb + X16_OFF);
  f16* WoT  = (f16*)(wsb + WOT_OFF);
  f16* hbuf = (f16*)(wsb + H_OFF);
  unsigned* flags = (unsigned*)(wsb + FLG_OFF);

  // zero h double-buffers (h0 = 0) and flags
  hipMemsetAsync(wsb + H_OFF, 0, ZERO_BYTES, stream);

  lstm_prepass<<<1024, 256, 0, stream>>>(x, Wout, x16, WoT);

  // 128 WGs x 512 threads; 139KB LDS -> 1 WG/CU, grid = half of capacity.
  lstm_main<<<128, 512, 0, stream>>>(W, b, x16, hbuf, flags);

  lstm_out<<<128, 256, 0, stream>>>(hbuf, WoT, bout, out);
}

// Round 10
// 2439.453 us; speedup vs baseline: 1.9251x; 1.0010x over previous
//
#include <hip/hip_runtime.h>

// LSTM B=64 T=512 IN=512 H=1024 OUT=512, all fp32 in/out.
// Persistent-RNN. R9 = R8 (best 2442us) with ONE change:
//   h + flag publication via global_atomic_swap ... sc1 (performed AT the LLC,
//   line allocated there) instead of sc0sc1 write-THROUGH stores (which the
//   R8 counters showed draining every h byte to HBM: WRITE_SIZE 82MB ≈
//   512 steps x 160KB -> store-ack and flag visibility were HBM-paced).
//   Epilogue lanes pair via shfl_xor: 2 f16 -> 1 u32 swap (32/wave vs 64).
// Everything else identical to R8: per-(WG,wave) flags, rolling dual poll,
// one __syncthreads/step, 128 WGs x 512 thr (1 WG/CU, 2x headroom).

#define B_   64
#define T_   512
#define IN_  512
#define H_   1024
#define G4_  4096   // 4*H
#define OUT_ 512

typedef _Float16 f16;
typedef _Float16 f16x8 __attribute__((ext_vector_type(8)));
typedef _Float16 f16x4 __attribute__((ext_vector_type(4)));
typedef float f32x4  __attribute__((ext_vector_type(4)));
typedef float f32x16 __attribute__((ext_vector_type(16)));

// workspace layout (bytes)
#define X16_OFF   0UL                         // [64][512][512] f16 = 33554432
#define WOT_OFF   33554432UL                  // W_out^T [512][1024] f16 = 1048576
#define H_OFF     (WOT_OFF + 1048576UL)       // h: [2 grp][2 buf][32][1024] f16 = 262144
#define FLG_OFF   (H_OFF + 262144UL)          // flags: [2 grp][64 slot][8 wave] u32 = 4096
#define WS_NEED   (FLG_OFF + 4096UL)
#define ZERO_BYTES (262144UL + 4096UL)        // h + flags zeroed together

__device__ __forceinline__ float sigmoidf_(float v) { return 1.f / (1.f + __expf(-v)); }
__device__ __forceinline__ float tanhf_(float v) { return 1.f - 2.f / (__expf(2.f * v) + 1.f); }

// Agent-coherent load: bypass L1 (sc0) and non-coherent per-XCD L2 (sc1);
// served at the LLC coherence point (hits the lines our atomics dirtied).
__device__ __forceinline__ f16x8 ld_agent_b128(const f16* p) {
  f16x8 r;
  asm volatile("global_load_dwordx4 %0, %1, off sc0 sc1" : "=v"(r) : "v"(p));
  return r;
}
// LLC-point publication: atomic swap (no return) performed AT the coherence
// point, allocating the line in LLC — no synchronous HBM write-through.
__device__ __forceinline__ void at_swap_b32(unsigned* p, unsigned v) {
  asm volatile("global_atomic_swap %0, %1, off sc1" :: "v"(p), "v"(v) : "memory");
}
// Flag load: issued async; NOT ready until an explicit s_waitcnt.
__device__ __forceinline__ unsigned ld_flag(const unsigned* p) {
  unsigned r;
  asm volatile("global_load_dword %0, %1, off sc0 sc1" : "=v"(r) : "v"(p));
  return r;
}
__device__ __forceinline__ void wait_vm0() {
  asm volatile("s_waitcnt vmcnt(0)" ::: "memory");
  __builtin_amdgcn_sched_barrier(0);
}
__device__ __forceinline__ void wait_vm1() {
  asm volatile("s_waitcnt vmcnt(1)" ::: "memory");
  __builtin_amdgcn_sched_barrier(0);
}

__global__ __launch_bounds__(256) void lstm_prepass(
    const float* __restrict__ x, const float* __restrict__ Wout,
    f16* __restrict__ x16, f16* __restrict__ WoT) {
  long i = (long)blockIdx.x * blockDim.x + threadIdx.x;
  long stride = (long)gridDim.x * blockDim.x;
  const long n4 = (long)B_ * T_ * IN_ / 4;
  const float4* x4 = (const float4*)x;
  f16x4* o4 = (f16x4*)x16;
  for (long p = i; p < n4; p += stride) {
    float4 v = x4[p];
    f16x4 o = { (f16)v.x, (f16)v.y, (f16)v.z, (f16)v.w };
    o4[p] = o;
  }
  const long nw = (long)H_ * OUT_;
  for (long p = i; p < nw; p += stride) {
    long k = p / OUT_, c = p % OUT_;
    WoT[c * (long)H_ + k] = (f16)Wout[p];
  }
}

// 128 WGs x 512 threads (8 waves). WG wg: group g = wg>>6 (rows g*32..g*32+31),
// wgi = wg&63 owns h-cols [wgi*16, wgi*16+16). 8 waves K-split over K=1536
// (x 64/wave, h 128/wave). Wave w's h K-range [128w,128w+128) is produced by
// slots 8w..8w+7; per-(slot,wave) flags -> consumer window = 64 contiguous u32.
__global__ __launch_bounds__(512, 2) void lstm_main(
    const float* __restrict__ W, const float* __restrict__ b,
    const f16* __restrict__ x16, f16* hbuf, unsigned* flags) {

  const int wg   = blockIdx.x;
  const int g    = wg >> 6;
  const int wgi  = wg & 63;
  const int tid  = threadIdx.x;
  const int wave = tid >> 6;    // 0..7
  const int lane = tid & 63;

  const int hbase   = wgi * 16;
  const int colLane = lane & 31;        // MFMA N index within tile
  const int khalf   = (lane >> 5) * 8;  // MFMA K sub-index
  const int arow    = lane & 31;        // MFMA M index (batch row in group)

  // ---- persistent W fragments (fp32 -> fp16, MFMA B layout), as R5 ----
  f16x8 wf[24];
  #pragma unroll
  for (int n = 0; n < 2; ++n) {
    const int gate = n * 2 + (colLane >> 4);
    const int gcol = gate * H_ + hbase + (colLane & 15);
    #pragma unroll
    for (int kf = 0; kf < 12; ++kf) {
      const int k0 = (kf < 4) ? (64 * wave + 16 * kf)
                              : (512 + 128 * wave + 16 * (kf - 4));
      f16x8 v;
      #pragma unroll
      for (int j = 0; j < 8; ++j)
        v[j] = (f16)W[(long)(k0 + khalf + j) * G4_ + gcol];
      wf[n * 12 + kf] = v;
    }
  }

  // epilogue ownership: thread -> (row erow 0..31, col offset ej 0..15).
  const int erow = tid >> 4;
  const int ej   = tid & 15;
  float bias[4];
  #pragma unroll
  for (int gt = 0; gt < 4; ++gt) bias[gt] = b[gt * H_ + hbase + ej];

  float c_state = 0.f;

  __shared__ float red[2][8][32][68];   // double-buffered -> 1 barrier/step

  const f16* xg = x16 + (long)(g * 32) * T_ * IN_;
  f16* hb       = hbuf + (long)g * 2 * 32 * H_;   // [2][32][1024]
  unsigned* flg = flags + g * 64 * 8;             // [slot][wave]

  // my poll word: (slot 8w + (lane>>3), wave lane&7) = flg[64*wave + lane]
  const unsigned* fp = flg + 64 * wave + lane;
  // my flag word (published by lane 0)
  unsigned* myflag = flg + wgi * 8 + wave;

  // ---- x-part of t=0 (h0 = 0 pre-zeroed in ws) ----
  f32x16 acc0 = {}, acc1 = {};
  {
    const f16* xrow = xg + (long)arow * (T_ * IN_) + 64 * wave + khalf;
    f16x8 xa[4];
    #pragma unroll
    for (int f = 0; f < 4; ++f) xa[f] = *(const f16x8*)(xrow + 16 * f);
    #pragma unroll
    for (int kf = 0; kf < 4; ++kf) {
      acc0 = __builtin_amdgcn_mfma_f32_32x32x16_f16(xa[kf], wf[kf],      acc0, 0, 0, 0);
      acc1 = __builtin_amdgcn_mfma_f32_32x32x16_f16(xa[kf], wf[12 + kf], acc1, 0, 0, 0);
    }
  }

  for (int t = 0; t < T_; ++t) {
    const int buf = t & 1;

    // ---- dual-outstanding rolling poll: my 64 producer-wave flags >= t ----
    if (t > 0) {
      const unsigned tgt = (unsigned)t;
      int guard = 0;
      unsigned v0 = ld_flag(fp);
      unsigned v1 = 0;
      for (;;) {
        v1 = ld_flag(fp);
        wait_vm1();                       // oldest (v0) retired
        if (__all(v0 >= tgt) || ++guard > (1 << 22)) break;
        v0 = ld_flag(fp);
        wait_vm1();                       // oldest (v1) retired
        if (__all(v1 >= tgt) || ++guard > (1 << 22)) break;
      }
      // retire the leftover in-flight poll load before its reg can be reused
      asm volatile("s_waitcnt vmcnt(0)" ::: "memory");
      asm volatile("" :: "v"(v0), "v"(v1));   // keep regs alive past drain
      __builtin_amdgcn_sched_barrier(0);
    }

    // ---- h-part: agent-coherent loads of my K-range of h_t ----
    {
      const f16* hrow = hb + (long)buf * (32 * H_) + (long)arow * H_
                           + 128 * wave + khalf;
      f16x8 ha[8];
      #pragma unroll
      for (int f = 0; f < 8; ++f)
        ha[f] = ld_agent_b128(hrow + 16 * f);
      wait_vm0();
      #pragma unroll
      for (int kf = 0; kf < 8; ++kf) {
        acc0 = __builtin_amdgcn_mfma_f32_32x32x16_f16(ha[kf], wf[4 + kf],  acc0, 0, 0, 0);
        acc1 = __builtin_amdgcn_mfma_f32_32x32x16_f16(ha[kf], wf[16 + kf], acc1, 0, 0, 0);
      }
    }

    // ---- cross-wave K-reduction via LDS (double-buffered) ----
    // C layout (32x32): col = lane&31, row = (r&3) + 8*(r>>2) + 4*(lane>>5)
    {
      float (*rb)[32][68] = red[buf];
      #pragma unroll
      for (int r = 0; r < 16; ++r) {
        const int row = (r & 3) + 8 * (r >> 2) + 4 * (lane >> 5);
        rb[wave][row][colLane]      = acc0[r];
        rb[wave][row][32 + colLane] = acc1[r];
      }
    }
    __syncthreads();   // the ONLY barrier per step

    // ---- epilogue: gates, c/h update, paired atomic publish ----
    {
      const float (*rb)[32][68] = red[buf];
      float f4[4];
      #pragma unroll
      for (int gt = 0; gt < 4; ++gt) {
        float s = bias[gt];
        #pragma unroll
        for (int w = 0; w < 8; ++w) s += rb[w][erow][gt * 16 + ej];
        f4[gt] = s;
      }
      const float fg = sigmoidf_(f4[0]);
      const float ig = sigmoidf_(f4[1]);
      const float gg = tanhf_(f4[2]);
      const float og = sigmoidf_(f4[3]);
      c_state = c_state * fg + ig * gg;
      const float hv = og * tanhf_(c_state);

      // pack 2 adjacent f16 (ej even|odd) into one u32; even lanes swap->LLC
      const unsigned h16 =
          (unsigned)__builtin_bit_cast(unsigned short, (f16)hv);
      const unsigned hi = (unsigned)__shfl_xor((int)h16, 1, 64);
      if ((lane & 1) == 0) {
        unsigned pk = h16 | (hi << 16);
        unsigned* p = (unsigned*)&hb[(long)(buf ^ 1) * (32 * H_)
                                     + (long)erow * H_ + hbase + ej];
        at_swap_b32(p, pk);
      }
      wait_vm0();                         // ack THIS wave's 32 LLC atomics
      if (lane == 0)
        at_swap_b32(myflag, (unsigned)(t + 1));
    }

    // ---- x-part of t+1 (after publish; never delays it) ----
    acc0 = f32x16{}; acc1 = f32x16{};
    if (t + 1 < T_) {
      const f16* xrow = xg + (long)arow * (T_ * IN_) + (long)(t + 1) * IN_
                           + 64 * wave + khalf;
      f16x8 xa[4];
      #pragma unroll
      for (int f = 0; f < 4; ++f) xa[f] = *(const f16x8*)(xrow + 16 * f);
      #pragma unroll
      for (int kf = 0; kf < 4; ++kf) {
        acc0 = __builtin_amdgcn_mfma_f32_32x32x16_f16(xa[kf], wf[kf],      acc0, 0, 0, 0);
        acc1 = __builtin_amdgcn_mfma_f32_32x32x16_f16(xa[kf], wf[12 + kf], acc1, 0, 0, 0);
      }
    }
  }
}

// out = h_T @ W_out + b_out : [64,1024]@[1024,512]. h_T is in h buf 0 (T even).
// 128 WGs: 4 row-tiles x 32 col-tiles of 16x16; 4 waves K-split 256 each.
__global__ __launch_bounds__(256) void lstm_out(
    const f16* __restrict__ hbuf, const f16* __restrict__ WoT,
    const float* __restrict__ bout, float* __restrict__ out) {
  const int wgid = blockIdx.x;
  const int rowT = wgid >> 5;   // 0..3
  const int colT = wgid & 31;   // 0..31
  const int tid  = threadIdx.x;
  const int wave = tid >> 6;
  const int lane = tid & 63;
  const int r16  = lane & 15;
  const int ksel = (lane >> 4) * 8;

  const int g = rowT >> 1;
  const f16* hrow = hbuf + (long)g * 2 * 32 * H_            // group base (buf 0)
                  + (long)((rowT & 1) * 16 + r16) * H_;
  const f16* wrow = WoT + (long)(colT * 16 + r16) * H_;

  f32x4 acc = {};
  #pragma unroll
  for (int f = 0; f < 8; ++f) {
    f16x8 a  = *(const f16x8*)(hrow + 256 * wave + 32 * f + ksel);
    f16x8 bf = *(const f16x8*)(wrow + 256 * wave + 32 * f + ksel);
    acc = __builtin_amdgcn_mfma_f32_16x16x32_f16(a, bf, acc, 0, 0, 0);
  }

  __shared__ float red[4][16][20];
  #pragma unroll
  for (int r = 0; r < 4; ++r)
    red[wave][(lane >> 4) * 4 + r][lane & 15] = acc[r];
  __syncthreads();

  const int row = tid >> 4;   // 0..15
  const int col = tid & 15;
  float s = bout[colT * 16 + col];
  #pragma unroll
  for (int w = 0; w < 4; ++w) s += red[w][row][col];
  out[(long)(rowT * 16 + row) * OUT_ + colT * 16 + col] = s;
}

extern "C" void kernel_launch(void* const* d_in, const int* in_sizes, int n_in,
                              void* d_out, int out_size, void* d_ws, size_t ws_size,
                              hipStream_t stream) {
  const float* x    = (const float*)d_in[0];
  const float* W    = (const float*)d_in[1];
  const float* b    = (const float*)d_in[2];
  const float* Wout = (const float*)d_in[3];
  const float* bout = (const float*)d_in[4];
  float* out = (float*)d_out;

  if (ws_size < WS_NEED) return;  // avoid corrupting memory if ws too small

  char* wsb = (char*)d_ws;
  f16* x16  = (f16*)(wsb + X16_OFF);
  f16* WoT  = (f16*)(wsb + WOT_OFF);
  f16* hbuf = (f16*)(wsb + H_OFF);
  unsigned* flags = (unsigned*)(wsb + FLG_OFF);

  // zero h double-buffers (h0 = 0) and flags
  hipMemsetAsync(wsb + H_OFF, 0, ZERO_BYTES, stream);

  lstm_prepass<<<1024, 256, 0, stream>>>(x, Wout, x16, WoT);

  // 128 WGs x 512 threads; 139KB LDS -> 1 WG/CU, grid = half of capacity.
  lstm_main<<<128, 512, 0, stream>>>(W, b, x16, hbuf, flags);

  lstm_out<<<128, 256, 0, stream>>>(hbuf, WoT, bout, out);
}